// Round 2
// baseline (332.800 us; speedup 1.0000x reference)
//
#include <hip/hip_runtime.h>
#include <hip/hip_bf16.h>

#define H  4096
#define V  4
#define OUT_N 4
#define MS 104
#define MD 3

__device__ __forceinline__ float b2f(unsigned short u) {
    return __uint_as_float(((unsigned int)u) << 16);
}
// Load element i of tensor p as float, interpreting storage per flag.
__device__ __forceinline__ float ldf(const void* p, size_t i, bool is_f32) {
    return is_f32 ? ((const float*)p)[i] : b2f(((const unsigned short*)p)[i]);
}
__device__ __forceinline__ void stf(void* p, size_t i, bool is_f32, float v) {
    if (is_f32) ((float*)p)[i] = v;
    else        ((__hip_bfloat16*)p)[i] = __float2bfloat16(v);
}

// ---------------------------------------------------------------------------
// Dtype detector: decode first 1024 ushorts of w_hh as bf16. Real bf16 weights
// are all |x| <~ 0.2. If storage is f32, the low-16-bit halves decode to
// random-exponent bf16 (42%/element chance of |x|>1e6) -> flag=1 (f32).
// ---------------------------------------------------------------------------
__global__ void detect_kernel(const unsigned short* __restrict__ w_hh_raw,
                              int* __restrict__ flag) {
    const int t = threadIdx.x;               // 64 threads, one wave
    int bad = 0;
    for (int i = t; i < 1024; i += 64) {
        const float v = b2f(w_hh_raw[i]);
        if (!(fabsf(v) < 1.0e6f)) bad = 1;   // catches inf/NaN bit patterns too
    }
    const unsigned long long m = __ballot(bad);
    if (t == 0) flag[0] = (m != 0ull) ? 1 : 0;
}

// ---------------------------------------------------------------------------
// h_bar[j] = w_sh[j,:] . stack[0,:] + b_sh[j] + hidden0[j]   (fp32 into ws)
// ---------------------------------------------------------------------------
__global__ __launch_bounds__(256) void hbar_kernel(
    const void* __restrict__ w_sh, const void* __restrict__ b_sh,
    const void* __restrict__ hidden0, const void* __restrict__ stack,
    const int* __restrict__ flag, float* __restrict__ h_bar) {
    const bool f32 = flag[0] != 0;
    const float s0 = ldf(stack, 0, f32);
    const float s1 = ldf(stack, 1, f32);
    const float s2 = ldf(stack, 2, f32);
    const int j = blockIdx.x * 256 + threadIdx.x;
    if (j < H) {
        h_bar[j] = ldf(w_sh, (size_t)j * 3 + 0, f32) * s0
                 + ldf(w_sh, (size_t)j * 3 + 1, f32) * s1
                 + ldf(w_sh, (size_t)j * 3 + 2, f32) * s2
                 + ldf(b_sh, j, f32) + ldf(hidden0, j, f32);
    }
}

// ---------------------------------------------------------------------------
// One block per hidden index k: three w_hh row-dots vs h_bar, then GRU gates.
// Scalar loads only (2B/4B aligned by construction), stride-256 per thread so
// consecutive lanes hit consecutive elements (coalesced 128B+/wave).
// ---------------------------------------------------------------------------
__global__ __launch_bounds__(256) void gru_kernel(
    const int*  __restrict__ inp,  const void* __restrict__ emb,
    const void* __restrict__ w_ih, const void* __restrict__ w_hh,
    const void* __restrict__ b_ih, const void* __restrict__ b_hh,
    const int*  __restrict__ flag, const float* __restrict__ h_bar,
    float* __restrict__ h_f32, void* __restrict__ out) {
    const bool f32 = flag[0] != 0;
    const int k = blockIdx.x, t = threadIdx.x;
    const size_t r0 = (size_t)k * H;
    const size_t r1 = (size_t)(k + H) * H;
    const size_t r2 = (size_t)(k + 2 * H) * H;

    float ar = 0.f, az = 0.f, an = 0.f;
    #pragma unroll 4
    for (int i = t; i < H; i += 256) {
        const float hb = h_bar[i];
        ar += ldf(w_hh, r0 + i, f32) * hb;
        az += ldf(w_hh, r1 + i, f32) * hb;
        an += ldf(w_hh, r2 + i, f32) * hb;
    }

    #pragma unroll
    for (int off = 32; off > 0; off >>= 1) {
        ar += __shfl_down(ar, off);
        az += __shfl_down(az, off);
        an += __shfl_down(an, off);
    }
    __shared__ float red[4][3];
    const int wave = t >> 6, lane = t & 63;
    if (lane == 0) { red[wave][0] = ar; red[wave][1] = az; red[wave][2] = an; }
    __syncthreads();

    if (t == 0) {
        const float sr = red[0][0] + red[1][0] + red[2][0] + red[3][0];
        const float sz = red[0][1] + red[1][1] + red[2][1] + red[3][1];
        const float sn = red[0][2] + red[1][2] + red[2][2] + red[3][2];

        const int idx = inp[0];
        float x[V];
        #pragma unroll
        for (int c = 0; c < V; ++c) x[c] = ldf(emb, (size_t)idx * V + c, f32);

        float gi[3];
        #pragma unroll
        for (int g = 0; g < 3; ++g) {
            float acc = ldf(b_ih, (size_t)(k + g * H), f32);
            #pragma unroll
            for (int c = 0; c < V; ++c)
                acc += ldf(w_ih, (size_t)(k + g * H) * V + c, f32) * x[c];
            gi[g] = acc;
        }
        const float ghr = sr + ldf(b_hh, (size_t)k,         f32);
        const float ghz = sz + ldf(b_hh, (size_t)(k + H),   f32);
        const float ghn = sn + ldf(b_hh, (size_t)(k + 2*H), f32);

        const float r = 1.f / (1.f + expf(-(gi[0] + ghr)));
        const float z = 1.f / (1.f + expf(-(gi[1] + ghz)));
        const float n = tanhf(gi[2] + r * ghn);
        const float hk = (1.f - z) * n + z * h_bar[k];

        h_f32[k] = hk;
        stf(out, (size_t)(OUT_N + k), f32, hk);   // hidden output
    }
}

// ---------------------------------------------------------------------------
// Heads: 9 row-dots vs h (fp32), sigmoid/softmax, differentiable stack blend.
// ---------------------------------------------------------------------------
__global__ __launch_bounds__(256) void heads_kernel(
    const float* __restrict__ h,
    const void* __restrict__ w_y, const void* __restrict__ b_y,
    const void* __restrict__ w_a, const void* __restrict__ b_a,
    const void* __restrict__ w_n, const void* __restrict__ b_n,
    const void* __restrict__ stack, const int* __restrict__ flag,
    void* __restrict__ out) {
    const bool f32 = flag[0] != 0;
    const int t = threadIdx.x;

    float acc[9];
    #pragma unroll
    for (int s = 0; s < 9; ++s) acc[s] = 0.f;

    for (int i = t; i < H; i += 256) {
        const float hv = h[i];
        #pragma unroll
        for (int s = 0; s < 4; ++s) acc[s]     += ldf(w_y, (size_t)s * H + i, f32) * hv;
        acc[4] += ldf(w_a, (size_t)i,     f32) * hv;
        acc[5] += ldf(w_a, (size_t)H + i, f32) * hv;
        #pragma unroll
        for (int s = 0; s < 3; ++s) acc[6 + s] += ldf(w_n, (size_t)s * H + i, f32) * hv;
    }

    __shared__ float scal[9];
    __shared__ float red[4];
    for (int s = 0; s < 9; ++s) {
        float a = acc[s];
        #pragma unroll
        for (int off = 32; off > 0; off >>= 1) a += __shfl_down(a, off);
        if ((t & 63) == 0) red[t >> 6] = a;
        __syncthreads();
        if (t == 0) scal[s] = red[0] + red[1] + red[2] + red[3];
        __syncthreads();
    }

    __shared__ float act0, act1, ne[MD];
    if (t == 0) {
        const float a0 = scal[4] + ldf(b_a, 0, f32);
        const float a1 = scal[5] + ldf(b_a, 1, f32);
        const float m  = fmaxf(a0, a1);
        const float e0 = expf(a0 - m), e1 = expf(a1 - m);
        const float inv = 1.f / (e0 + e1);
        act0 = e0 * inv; act1 = e1 * inv;
    }
    if (t < OUT_N)
        stf(out, (size_t)t, f32,
            1.f / (1.f + expf(-(scal[t] + ldf(b_y, t, f32)))));
    if (t < MD)
        ne[t] = 1.f / (1.f + expf(-(scal[6 + t] + ldf(b_n, t, f32))));
    __syncthreads();

    const float a0 = act0, a1 = act1;
    for (int idx = t; idx < MS * MD; idx += 256) {
        const int i = idx / MD;
        const int d = idx - i * MD;
        const float push = (i == 0)      ? ne[d] : ldf(stack, (size_t)(idx - MD), f32);
        const float pop  = (i == MS - 1) ? 0.f   : ldf(stack, (size_t)(idx + MD), f32);
        stf(out, (size_t)(OUT_N + H + idx), f32, a0 * push + a1 * pop);
    }
}

extern "C" void kernel_launch(void* const* d_in, const int* in_sizes, int n_in,
                              void* d_out, int out_size, void* d_ws, size_t ws_size,
                              hipStream_t stream) {
    const int* inp      = (const int*)d_in[0];
    const void* hidden0 = d_in[1];
    const void* stack   = d_in[2];
    const void* emb     = d_in[3];
    const void* w_ih    = d_in[4];
    const void* w_hh    = d_in[5];
    const void* b_ih    = d_in[6];
    const void* b_hh    = d_in[7];
    const void* w_y     = d_in[8];
    const void* b_y     = d_in[9];
    const void* w_n     = d_in[10];
    const void* b_n     = d_in[11];
    const void* w_a     = d_in[12];
    const void* b_a     = d_in[13];
    const void* w_sh    = d_in[14];
    const void* b_sh    = d_in[15];

    int*   flag  = (int*)d_ws;
    float* h_bar = (float*)((char*)d_ws + 16);
    float* h     = h_bar + H;

    detect_kernel<<<1, 64, 0, stream>>>((const unsigned short*)w_hh, flag);
    hbar_kernel<<<(H + 255) / 256, 256, 0, stream>>>(w_sh, b_sh, hidden0, stack,
                                                     flag, h_bar);
    gru_kernel<<<H, 256, 0, stream>>>(inp, emb, w_ih, w_hh, b_ih, b_hh,
                                      flag, h_bar, h, d_out);
    heads_kernel<<<1, 256, 0, stream>>>(h, w_y, b_y, w_a, b_a, w_n, b_n,
                                        stack, flag, d_out);
}